// Round 5
// baseline (60.710 us; speedup 1.0000x reference)
//
#include <hip/hip_runtime.h>
#include <stdint.h>

// AeTransformer_44839458570443: 3-NN inverse-distance interpolation + (tanh+1)/2.
// xyz1: [B,3,N] fp32, xyz2: [B,3,S] fp32, points2: [B,1,S] fp32 -> out [B,N] fp32.
//
// Selection bit-matches the reference's float32 expanded distance
//   d = (-2*((x*x'+y*y')+z*z') + ||q||^2) + ||p||^2    (fp32, no FMA)
// ordered by (d, index). SCREEN: packed-fp32 (v_pk_fma) proxy keys
// (quantized d | idx) in a sorted 6-slot min-list (v_med3), candidate table
// read via the scalar path (SMEM) from a SoA layout. REFINE: 6 survivors
// re-scored with the exact replicated fp32 sequence, sorted by (d, idx).
static constexpr int B = 4;
static constexpr int N = 65536;
static constexpr int S = 512;

typedef float float2v __attribute__((ext_vector_type(2)));

// ws layout per batch (4096 floats = 16 KB; total 64 KB):
//   [0..511]    X   [512..1023]  Y   [1024..1535] Z   [1536..2047] W=||p||^2
//   [2048..4095] AoS float4 {x,y,z,||p||^2}  (refine table)
__global__ __launch_bounds__(256) void prep_kernel(const float* __restrict__ xyz2,
                                                   float* __restrict__ wsf) {
    int t = blockIdx.x * 256 + threadIdx.x;
    if (t >= B * S) return;
    int b = t >> 9, s = t & 511;
    const float* p = xyz2 + (size_t)b * 3 * S;
    float x = p[s], y = p[s + S], z = p[s + 2 * S];
    float c = __fadd_rn(__fadd_rn(__fmul_rn(x, x), __fmul_rn(y, y)), __fmul_rn(z, z));
    float* base = wsf + (size_t)b * 4096;
    base[s] = x;
    base[s + 512] = y;
    base[s + 1024] = z;
    base[s + 1536] = c;
    ((float4*)(base + 2048))[s] = make_float4(x, y, z, c);
}

// Reference-replicated fp32 distance (numpy order, no contraction)
__device__ __forceinline__ float ref_d(float x1, float y1, float z1, float ssrc, float4 p) {
    float dot = __fadd_rn(__fadd_rn(__fmul_rn(x1, p.x), __fmul_rn(y1, p.y)),
                          __fmul_rn(z1, p.z));
    float t = __fmul_rn(dot, -2.0f);
    return __fadd_rn(__fadd_rn(t, ssrc), p.w);
}

// compare-and-swap on (d, idx) ascending, idx ascending on exact float ties
#define CAS(da_, ia_, db_, ib_)                                     \
    {                                                               \
        bool sw_ = (db_ < da_) || ((db_ == da_) && (ib_ < ia_));    \
        float tda_ = sw_ ? db_ : da_;                               \
        int tia_ = sw_ ? ib_ : ia_;                                 \
        db_ = sw_ ? da_ : db_;                                      \
        ib_ = sw_ ? ia_ : ib_;                                      \
        da_ = tda_;                                                 \
        ia_ = tia_;                                                 \
    }

// branchless sorted insert of key k into ascending 6-list m0..m5
#define INS6(k)                                                     \
    {                                                               \
        float t5 = __builtin_amdgcn_fmed3f(m4, (k), m5);            \
        float t4 = __builtin_amdgcn_fmed3f(m3, (k), m4);            \
        float t3 = __builtin_amdgcn_fmed3f(m2, (k), m3);            \
        float t2 = __builtin_amdgcn_fmed3f(m1, (k), m2);            \
        float t1 = __builtin_amdgcn_fmed3f(m0, (k), m1);            \
        m0 = fminf(m0, (k));                                        \
        m1 = t1; m2 = t2; m3 = t3; m4 = t4; m5 = t5;                \
    }

__global__ __launch_bounds__(256) void knn3_kernel(const float* __restrict__ xyz1,
                                                   const float* __restrict__ points2,
                                                   const float* __restrict__ wsf,
                                                   float* __restrict__ out) {
    // block-uniform batch index (from blockIdx only -> provably uniform)
    const int b = blockIdx.x >> 8;               // 256 blocks per batch
    const int n = ((blockIdx.x & 255) << 8) | threadIdx.x;
    const int b_u = __builtin_amdgcn_readfirstlane(b);

    const float* q = xyz1 + (size_t)b * 3 * N;
    float x1 = q[n], y1 = q[n + N], z1 = q[n + 2 * N];
    float ssrc = __fadd_rn(__fadd_rn(__fmul_rn(x1, x1), __fmul_rn(y1, y1)),
                           __fmul_rn(z1, z1));
    // screen-only per-query constants (proxy zone; refine is exact)
    float c = ssrc + 0.25f;  // bias keeps key > 0
    float2v nx2 = {-2.0f * x1, -2.0f * x1};
    float2v ny2 = {-2.0f * y1, -2.0f * y1};
    float2v nz2 = {-2.0f * z1, -2.0f * z1};
    float2v cc = {c, c};

    // wave-uniform SoA table pointers -> scalar s_load path
    const float* base = wsf + (size_t)b_u * 4096;
    const float2v* __restrict__ Xp = (const float2v*)base;
    const float2v* __restrict__ Yp = (const float2v*)(base + 512);
    const float2v* __restrict__ Zp = (const float2v*)(base + 1024);
    const float2v* __restrict__ Wp = (const float2v*)(base + 1536);

    // 6 smallest packed keys ascending; key = float(proxy d + 0.25) with low
    // 9 mantissa bits = candidate index (monotone bucket, idx tiebreak).
    float m0 = 3.0e38f, m1 = 3.0e38f, m2 = 3.0e38f,
          m3 = 3.0e38f, m4 = 3.0e38f, m5 = 3.0e38f;
    uint32_t idxv = 0;
#pragma unroll 4
    for (int s2 = 0; s2 < 256; ++s2) {
        float2v xp = Xp[s2], yp = Yp[s2], zp = Zp[s2], wp = Wp[s2];
        float2v t = wp + cc;                          // v_pk_add_f32
        t = __builtin_elementwise_fma(nz2, zp, t);    // v_pk_fma_f32
        t = __builtin_elementwise_fma(ny2, yp, t);
        t = __builtin_elementwise_fma(nx2, xp, t);
        float k0 = __uint_as_float((__float_as_uint(t.x) & 0xFFFFFE00u) | idxv);
        INS6(k0);
        ++idxv;
        float k1 = __uint_as_float((__float_as_uint(t.y) & 0xFFFFFE00u) | idxv);
        INS6(k1);
        ++idxv;
    }

    // Re-score the 6 survivors with the exact replicated fp32 distance (AoS
    // gather), then sort exactly by (d, idx).
    const float4* __restrict__ at = (const float4*)(base + 2048);
    int gi[6];
    float dd[6];
    gi[0] = (int)(__float_as_uint(m0) & 511u);
    gi[1] = (int)(__float_as_uint(m1) & 511u);
    gi[2] = (int)(__float_as_uint(m2) & 511u);
    gi[3] = (int)(__float_as_uint(m3) & 511u);
    gi[4] = (int)(__float_as_uint(m4) & 511u);
    gi[5] = (int)(__float_as_uint(m5) & 511u);
#pragma unroll
    for (int j = 0; j < 6; ++j) dd[j] = ref_d(x1, y1, z1, ssrc, at[gi[j]]);

    // selection network: bubble smallest 3 to front by (d, idx)
#pragma unroll
    for (int p = 0; p < 3; ++p)
#pragma unroll
        for (int i = 4; i >= p; --i) CAS(dd[i], gi[i], dd[i + 1], gi[i + 1]);

    // Replicate reference weight/interp chain in fp32, nearest-first order
    const float EPS32 = 1e-8f;
    float r0 = __fdiv_rn(1.0f, __fadd_rn(dd[0], EPS32));
    float r1 = __fdiv_rn(1.0f, __fadd_rn(dd[1], EPS32));
    float r2 = __fdiv_rn(1.0f, __fadd_rn(dd[2], EPS32));
    float rs = __fadd_rn(__fadd_rn(r0, r1), r2);
    float w0 = __fdiv_rn(r0, rs);
    float w1 = __fdiv_rn(r1, rs);
    float w2 = __fdiv_rn(r2, rs);
    const float* f = points2 + (size_t)b * S;  // D = 1
    float interp = __fadd_rn(__fadd_rn(__fmul_rn(f[gi[0]], w0), __fmul_rn(f[gi[1]], w1)),
                             __fmul_rn(f[gi[2]], w2));
    float t = tanhf(interp);
    out[((size_t)b << 16) | (uint32_t)n] = __fmul_rn(__fadd_rn(t, 1.0f), 0.5f);
}

extern "C" void kernel_launch(void* const* d_in, const int* in_sizes, int n_in,
                              void* d_out, int out_size, void* d_ws, size_t ws_size,
                              hipStream_t stream) {
    const float* xyz1 = (const float*)d_in[0];
    const float* xyz2 = (const float*)d_in[1];
    const float* points2 = (const float*)d_in[2];
    float* out = (float*)d_out;
    float* wsf = (float*)d_ws;  // 64 KB: SoA screen tables + AoS refine tables

    prep_kernel<<<(B * S + 255) / 256, 256, 0, stream>>>(xyz2, wsf);
    knn3_kernel<<<(B * N) / 256, 256, 0, stream>>>(xyz1, points2, wsf, out);
}

// Round 6
// 39.013 us; speedup vs baseline: 1.5561x; 1.5561x over previous
//
#include <hip/hip_runtime.h>
#include <stdint.h>

// AeTransformer_44839458570443: 3-NN inverse-distance interpolation + (tanh+1)/2.
// xyz1: [B,3,N] fp32, xyz2: [B,3,S] fp32, points2: [B,1,S] fp32 -> out [B,N] fp32.
//
// Selection bit-matches the reference fp32 expanded distance
//   d = (-2*((x*x'+y*y')+z*z') + ||q||^2) + ||p||^2   (fp32, no FMA)
// ordered by (d, index).
// PHASE A/B (cheap proxy scan): 64 groups of 8; per group, FMA distances +
//   min-tree -> group min; keep 5 smallest group keys (group id in low 6
//   mantissa bits). Lemma: any group holding a true top-3 element has
//   group-min <= d3, and at most 3 groups can satisfy that -> top-3 subset of
//   the 3 (we keep 5 for proxy-error margin) best groups.
// PHASE C: exact replicated ref_d over the 40 survivors, quantized 6-slot
//   screen + exact (d,idx) refine — proven in rounds 2-5.
static constexpr int B = 4;
static constexpr int N = 65536;
static constexpr int S = 512;

// Pack per-sample constants: (x, y, z, ((x*x + y*y) + z*z)) with IEEE fp32 ops
__global__ __launch_bounds__(256) void prep_kernel(const float* __restrict__ xyz2,
                                                   float4* __restrict__ ws) {
    int t = blockIdx.x * 256 + threadIdx.x;
    if (t >= B * S) return;
    int b = t >> 9, s = t & 511;
    const float* p = xyz2 + (size_t)b * 3 * S;
    float x = p[s], y = p[s + S], z = p[s + 2 * S];
    float c = __fadd_rn(__fadd_rn(__fmul_rn(x, x), __fmul_rn(y, y)), __fmul_rn(z, z));
    ws[t] = make_float4(x, y, z, c);
}

// Reference-replicated fp32 distance (numpy order, no contraction)
__device__ __forceinline__ float ref_d(float x1, float y1, float z1, float ssrc, float4 p) {
    float dot = __fadd_rn(__fadd_rn(__fmul_rn(x1, p.x), __fmul_rn(y1, p.y)),
                          __fmul_rn(z1, p.z));
    float t = __fmul_rn(dot, -2.0f);
    return __fadd_rn(__fadd_rn(t, ssrc), p.w);
}

// compare-and-swap on (d, idx) ascending, idx ascending on exact float ties
#define CAS(da_, ia_, db_, ib_)                                     \
    {                                                               \
        bool sw_ = (db_ < da_) || ((db_ == da_) && (ib_ < ia_));    \
        float tda_ = sw_ ? db_ : da_;                               \
        int tia_ = sw_ ? ib_ : ia_;                                 \
        db_ = sw_ ? da_ : db_;                                      \
        ib_ = sw_ ? ia_ : ib_;                                      \
        da_ = tda_;                                                 \
        ia_ = tia_;                                                 \
    }

// branchless sorted insert of key k into ascending 5-list g0..g4
#define INS5(k)                                                     \
    {                                                               \
        float t4 = __builtin_amdgcn_fmed3f(g3, (k), g4);            \
        float t3 = __builtin_amdgcn_fmed3f(g2, (k), g3);            \
        float t2 = __builtin_amdgcn_fmed3f(g1, (k), g2);            \
        float t1 = __builtin_amdgcn_fmed3f(g0, (k), g1);            \
        g0 = fminf(g0, (k));                                        \
        g1 = t1; g2 = t2; g3 = t3; g4 = t4;                         \
    }

// branchless sorted insert of key k into ascending 6-list m0..m5
#define INS6(k)                                                     \
    {                                                               \
        float t5 = __builtin_amdgcn_fmed3f(m4, (k), m5);            \
        float t4 = __builtin_amdgcn_fmed3f(m3, (k), m4);            \
        float t3 = __builtin_amdgcn_fmed3f(m2, (k), m3);            \
        float t2 = __builtin_amdgcn_fmed3f(m1, (k), m2);            \
        float t1 = __builtin_amdgcn_fmed3f(m0, (k), m1);            \
        m0 = fminf(m0, (k));                                        \
        m1 = t1; m2 = t2; m3 = t3; m4 = t4; m5 = t5;                \
    }

__global__ __launch_bounds__(256) void knn3_kernel(const float* __restrict__ xyz1,
                                                   const float* __restrict__ points2,
                                                   const float4* __restrict__ ws,
                                                   float* __restrict__ out) {
    __shared__ float4 tile[S];  // 8 KB candidate table
    const int b = blockIdx.x >> 8;               // 256 blocks per batch
    const int n = ((blockIdx.x & 255) << 8) | threadIdx.x;

    const float4* __restrict__ wsrc = ws + b * S;
    tile[threadIdx.x] = wsrc[threadIdx.x];
    tile[threadIdx.x + 256] = wsrc[threadIdx.x + 256];
    __syncthreads();

    const float* q = xyz1 + (size_t)b * 3 * N;
    float x1 = q[n], y1 = q[n + N], z1 = q[n + 2 * N];
    float ssrc = __fadd_rn(__fadd_rn(__fmul_rn(x1, x1), __fmul_rn(y1, y1)),
                           __fmul_rn(z1, z1));
    // screen-only constants (proxy zone; phases C uses exact ref_d)
    float c = ssrc + 0.25f;  // per-group bias; keeps packed keys > 0
    float nx2 = -2.0f * x1, ny2 = -2.0f * y1, nz2 = -2.0f * z1;

    // ---- Phase A/B: group scan, keep 5 best (group-min | group-id) keys ----
    float g0 = 3.0e38f, g1 = 3.0e38f, g2 = 3.0e38f, g3 = 3.0e38f, g4 = 3.0e38f;
    for (int g = 0; g < 64; ++g) {
        float e[8];
#pragma unroll
        for (int j = 0; j < 8; ++j) {
            float4 p = tile[g * 8 + j];  // uniform address -> ds_read broadcast
            // proxy: -2*dot + ||p||^2  (query-uniform terms added per group)
            e[j] = fmaf(nx2, p.x, fmaf(ny2, p.y, fmaf(nz2, p.z, p.w)));
        }
        // min tree (8 -> 1): nested fminf fuses to v_min3_f32
        float mA = fminf(fminf(e[0], e[1]), e[2]);
        float mB = fminf(fminf(e[3], e[4]), e[5]);
        float mC = fminf(fminf(mA, mB), e[6]);
        float gm = fminf(mC, e[7]);
        // pack group id into low 6 mantissa bits (value > 0 -> uint order)
        float gk = __uint_as_float((__float_as_uint(gm + c) & 0xFFFFFFC0u) | (uint32_t)g);
        INS5(gk);
    }

    // ---- Phase C: exact rescore of the 5 winning groups (40 candidates) ----
    float m0 = 3.0e38f, m1 = 3.0e38f, m2 = 3.0e38f,
          m3 = 3.0e38f, m4 = 3.0e38f, m5 = 3.0e38f;
    float gkeys[5] = {g0, g1, g2, g3, g4};
#pragma unroll
    for (int t = 0; t < 5; ++t) {
        int base = (int)(__float_as_uint(gkeys[t]) & 63u) * 8;
#pragma unroll
        for (int j = 0; j < 8; ++j) {
            float4 p = tile[base + j];  // per-lane divergent LDS gather
            float d = ref_d(x1, y1, z1, ssrc, p);
            float e2 = __fadd_rn(d, 0.25f);
            float k = __uint_as_float((__float_as_uint(e2) & 0xFFFFFE00u) |
                                      (uint32_t)(base + j));
            INS6(k);
        }
    }

    // ---- Refine: re-score 6 survivors exactly, sort by (d, idx) ----
    int gi[6];
    float dd[6];
    gi[0] = (int)(__float_as_uint(m0) & 511u);
    gi[1] = (int)(__float_as_uint(m1) & 511u);
    gi[2] = (int)(__float_as_uint(m2) & 511u);
    gi[3] = (int)(__float_as_uint(m3) & 511u);
    gi[4] = (int)(__float_as_uint(m4) & 511u);
    gi[5] = (int)(__float_as_uint(m5) & 511u);
#pragma unroll
    for (int j = 0; j < 6; ++j) dd[j] = ref_d(x1, y1, z1, ssrc, tile[gi[j]]);

#pragma unroll
    for (int p = 0; p < 3; ++p)
#pragma unroll
        for (int i = 4; i >= p; --i) CAS(dd[i], gi[i], dd[i + 1], gi[i + 1]);

    // Replicate reference weight/interp chain in fp32, nearest-first order
    const float EPS32 = 1e-8f;
    float r0 = __fdiv_rn(1.0f, __fadd_rn(dd[0], EPS32));
    float r1 = __fdiv_rn(1.0f, __fadd_rn(dd[1], EPS32));
    float r2 = __fdiv_rn(1.0f, __fadd_rn(dd[2], EPS32));
    float rs = __fadd_rn(__fadd_rn(r0, r1), r2);
    float w0 = __fdiv_rn(r0, rs);
    float w1 = __fdiv_rn(r1, rs);
    float w2 = __fdiv_rn(r2, rs);
    const float* f = points2 + (size_t)b * S;  // D = 1
    float interp = __fadd_rn(__fadd_rn(__fmul_rn(f[gi[0]], w0), __fmul_rn(f[gi[1]], w1)),
                             __fmul_rn(f[gi[2]], w2));
    float t = tanhf(interp);
    out[((size_t)b << 16) | (uint32_t)n] = __fmul_rn(__fadd_rn(t, 1.0f), 0.5f);
}

extern "C" void kernel_launch(void* const* d_in, const int* in_sizes, int n_in,
                              void* d_out, int out_size, void* d_ws, size_t ws_size,
                              hipStream_t stream) {
    const float* xyz1 = (const float*)d_in[0];
    const float* xyz2 = (const float*)d_in[1];
    const float* points2 = (const float*)d_in[2];
    float* out = (float*)d_out;
    float4* ws = (float4*)d_ws;  // B*S*16 = 32 KB

    prep_kernel<<<(B * S + 255) / 256, 256, 0, stream>>>(xyz2, ws);
    knn3_kernel<<<(B * N) / 256, 256, 0, stream>>>(xyz1, points2, ws, out);
}